// Round 2
// baseline (308.339 us; speedup 1.0000x reference)
//
#include <hip/hip_runtime.h>

#define N_NODES 50000
#define N_EDGES 400000
#define N_REL 6
#define NSEG (N_NODES * N_REL)
#define NTILE ((N_NODES + 63) / 64)   // 782 row tiles

#define SCAN_TILE 1024
#define SCAN_NB ((NSEG + SCAN_TILE - 1) / SCAN_TILE)

typedef float4 f4;
typedef short bf16x8 __attribute__((ext_vector_type(8)));
typedef float f32x4 __attribute__((ext_vector_type(4)));
typedef float f32x16 __attribute__((ext_vector_type(16)));
typedef int i32x8 __attribute__((ext_vector_type(8)));
typedef int i32x4 __attribute__((ext_vector_type(4)));

typedef __attribute__((address_space(1))) const void gvoid_t;
typedef __attribute__((address_space(3))) void lvoid_t;

__device__ __forceinline__ void gl_lds16(const void* g, void* l) {
    __builtin_amdgcn_global_load_lds((gvoid_t*)g, (lvoid_t*)l, 16, 0, 0);
}

__device__ __forceinline__ unsigned enc_f32(float f) {
    unsigned u = __float_as_uint(f);
    return (u & 0x80000000u) ? ~u : (u | 0x80000000u);
}
__device__ __forceinline__ float dec_f32(unsigned e) {
    return __uint_as_float((e & 0x80000000u) ? (e ^ 0x80000000u) : ~e);
}
__device__ __forceinline__ unsigned short bf16_rne(float x) {
    unsigned u = __float_as_uint(x);
    return (unsigned short)((u + 0x7FFFu + ((u >> 16) & 1u)) >> 16);
}
// pack 4 floats -> 4 fp8 e4m3 bytes (RNE, saturating)
__device__ __forceinline__ unsigned fp8x4(float a0, float a1, float a2, float a3) {
    unsigned r = __builtin_amdgcn_cvt_pk_fp8_f32(a0, a1, 0, 0);
    r = __builtin_amdgcn_cvt_pk_fp8_f32(a2, a3, r, 1);
    return r;
}
__device__ __forceinline__ unsigned char fp8_1(float v) {
    return (unsigned char)(__builtin_amdgcn_cvt_pk_fp8_f32(v, v, 0, 0) & 0xFF);
}

// bf16 LDS swizzle (layer-0 GEMM): 64B rows, 16B slots XOR'd
#define SWZ(row, slot) ((size_t)(row) * 32 + (((slot) ^ (((row) >> 1) & 3)) * 8))

// ================= CSR build =================
__global__ void count_seg(const int* __restrict__ ei, const int* __restrict__ et,
                          int* __restrict__ cnt) {
    int e = blockIdx.x * blockDim.x + threadIdx.x;
    if (e < N_EDGES) atomicAdd(&cnt[ei[N_EDGES + e] * N_REL + et[e]], 1);
}

__global__ void scan1(int* __restrict__ cnt, int* __restrict__ bsum) {
    __shared__ int sh[256];
    int t = threadIdx.x, b = blockIdx.x;
    int base = b * SCAN_TILE + t * 4;
    int v[4]; int s = 0;
    #pragma unroll
    for (int i = 0; i < 4; ++i) {
        v[i] = (base + i < NSEG) ? cnt[base + i] : 0;
        s += v[i];
    }
    sh[t] = s; __syncthreads();
    for (int o = 1; o < 256; o <<= 1) {
        int x = (t >= o) ? sh[t - o] : 0;
        __syncthreads();
        sh[t] += x;
        __syncthreads();
    }
    int run = sh[t] - s;
    #pragma unroll
    for (int i = 0; i < 4; ++i) {
        if (base + i < NSEG) cnt[base + i] = run;
        run += v[i];
    }
    if (t == 255) bsum[b] = sh[255];
}

__global__ void scan2(int* __restrict__ bsum) {
    __shared__ int sh[512];
    int t = threadIdx.x;
    int v = (t < SCAN_NB) ? bsum[t] : 0;
    sh[t] = v; __syncthreads();
    for (int o = 1; o < 512; o <<= 1) {
        int x = (t >= o) ? sh[t - o] : 0;
        __syncthreads();
        sh[t] += x;
        __syncthreads();
    }
    if (t < SCAN_NB) bsum[t] = sh[t] - v;
}

__global__ void scan3(const int* __restrict__ part, const int* __restrict__ bsum,
                      int* __restrict__ rowptr, int* __restrict__ fillptr) {
    int t = threadIdx.x, b = blockIdx.x;
    int base = b * SCAN_TILE + t * 4;
    int off = bsum[b];
    #pragma unroll
    for (int i = 0; i < 4; ++i) {
        if (base + i < NSEG) {
            int v = part[base + i] + off;
            rowptr[base + i] = v;
            fillptr[base + i] = v;
        }
    }
    if (b == 0 && t == 0) rowptr[NSEG] = N_EDGES;
}

__global__ void fill_edges(const int* __restrict__ ei, const int* __restrict__ et,
                           int* __restrict__ fillptr, int* __restrict__ esrc) {
    int e = blockIdx.x * blockDim.x + threadIdx.x;
    if (e < N_EDGES) {
        int seg = ei[N_EDGES + e] * N_REL + et[e];
        int p = atomicAdd(&fillptr[seg], 1);
        esrc[p] = ei[e];
    }
}

__global__ void rcp_kernel(const int* __restrict__ rowptr, float* __restrict__ rcp) {
    int s = blockIdx.x * blockDim.x + threadIdx.x;
    if (s < NSEG) {
        int c = rowptr[s + 1] - rowptr[s];
        rcp[s] = 1.0f / (float)(c > 1 ? c : 1);
    }
}

// ====== layer-0 weight prep (bf16, row-major Wt[n][k]) ======
__global__ void prep_w0(const float* __restrict__ Wf, const float* __restrict__ rootW,
                        unsigned short* __restrict__ Wt,
                        int K1, int din, int dout, int KB) {
    int k = blockIdx.x;
    int n = blockIdx.y * 256 + threadIdx.x;
    if (n >= dout) return;
    float v = 0.f;
    if (k < K1) v = Wf[(size_t)k * dout + n];
    else if (k < K1 + din) v = rootW[(size_t)(k - K1) * dout + n];
    Wt[(size_t)n * KB + k] = bf16_rne(v);
}

// ====== layers 1-2 weight prep: fp8 pair tiles for MX (plain K-major rows) ======
// pair p = k>>6. Wpk[ct][p][n 0..255][64]: byte = (ct*28+p)*16384 + n*64 + (k&63)
// value scaled x16 (undone by MFMA scale_b = 2^-4)
__global__ void prep_wpk8(const float* __restrict__ Wf, const float* __restrict__ rootW,
                          unsigned char* __restrict__ Wpk, int K1, int dout) {
    int k = blockIdx.x;                 // 0..1791
    int ct = blockIdx.y;
    int nl = threadIdx.x;               // 0..255
    int col = ct * 256 + nl;
    float v = (k < K1) ? Wf[(size_t)k * dout + col]
                       : rootW[(size_t)(k - K1) * dout + col];
    v *= 16.0f;
    int p = k >> 6;
    Wpk[((size_t)(ct * 28 + p)) * 16384 + (size_t)nl * 64 + (k & 63)] = fp8_1(v);
}

// ================= layer-0 aggregation (din=20) =================
__global__ void gather0(const float* __restrict__ x, const int* __restrict__ rowptr,
                        const int* __restrict__ esrc, const float* __restrict__ rcp,
                        unsigned short* __restrict__ Abf0) {
    int idx = blockIdx.x * blockDim.x + threadIdx.x;
    if (idx >= NSEG * 5) return;
    int s = idx / 5, q = idx - s * 5;
    float ax = 0.f, ay = 0.f, az = 0.f, aw = 0.f;
    int e0 = rowptr[s], e1 = rowptr[s + 1];
    for (int e = e0; e < e1; ++e) {
        const f4 u = *(const f4*)&x[(size_t)esrc[e] * 20 + q * 4];
        ax += u.x; ay += u.y; az += u.z; aw += u.w;
    }
    float sc = rcp[s];
    int node = s / N_REL, rel = s - node * N_REL;
    unsigned short* p = &Abf0[(size_t)node * 160 + rel * 20 + q * 4];
    unsigned o0 = bf16_rne(ax * sc) | ((unsigned)bf16_rne(ay * sc) << 16);
    unsigned o1 = bf16_rne(az * sc) | ((unsigned)bf16_rne(aw * sc) << 16);
    *(unsigned*)(p + 0) = o0;
    *(unsigned*)(p + 2) = o1;
}

__global__ void copyx0(const float* __restrict__ x, unsigned short* __restrict__ Abf0) {
    int t = blockIdx.x * blockDim.x + threadIdx.x;
    int n = t >> 5, d = t & 31;
    if (n >= N_NODES || d >= 20) return;
    Abf0[(size_t)n * 160 + 120 + d] = bf16_rne(x[(size_t)n * 20 + d]);
}

// ====== combined gather + root pack (layers 1,2), fp8 h in, MX pair-packed Apk ======
// pair tile 4KB: byte = (rt*28+p)*4096 + m*64 + phys_slot*16 + (k&15)
//   logical slot = (k_in_pair)>>4 (4 x 16B contiguous K); phys = (slot + (m>>1))&3
__global__ void gather_all8(const unsigned char* __restrict__ h8, const int* __restrict__ rowptr,
                            const int* __restrict__ esrc, const float* __restrict__ rcp,
                            unsigned char* __restrict__ Apk) {
    int t = blockIdx.x * blockDim.x + threadIdx.x;
    int sl = t >> 3;
    int q = t & 7;
    if (sl < NSEG) {
        int e0 = rowptr[sl], e1 = rowptr[sl + 1];
        float a[32];
        #pragma unroll
        for (int i = 0; i < 32; ++i) a[i] = 0.f;
        for (int e = e0; e < e1; ++e) {
            const unsigned char* hp = &h8[(size_t)esrc[e] * 256 + q * 32];
            #pragma unroll
            for (int c = 0; c < 2; ++c) {
                int4 v = *(const int4*)&hp[c * 16];
                const unsigned* pu = (const unsigned*)&v;
                #pragma unroll
                for (int j = 0; j < 4; ++j) {
                    unsigned u = pu[j];
                    a[c * 16 + j * 4 + 0] += __builtin_amdgcn_cvt_f32_fp8(u, 0);
                    a[c * 16 + j * 4 + 1] += __builtin_amdgcn_cvt_f32_fp8(u, 1);
                    a[c * 16 + j * 4 + 2] += __builtin_amdgcn_cvt_f32_fp8(u, 2);
                    a[c * 16 + j * 4 + 3] += __builtin_amdgcn_cvt_f32_fp8(u, 3);
                }
            }
        }
        float sc = rcp[sl];
        int node = sl / 6, rel = sl - node * 6;
        int rt = node >> 6, m = node & 63;
        int ks = rel * 8 + q;
        unsigned ow[8];
        #pragma unroll
        for (int i = 0; i < 8; ++i)
            ow[i] = fp8x4(a[4 * i] * sc, a[4 * i + 1] * sc, a[4 * i + 2] * sc, a[4 * i + 3] * sc);
        int p = ks >> 1, sp = ks & 1;
        unsigned char* dst = Apk + ((size_t)(rt * 28 + p)) * 4096 + (size_t)m * 64;
        int rot = (m >> 1) & 3;
        *(int4*)(dst + (((sp * 2 + 0 + rot) & 3) * 16)) = make_int4(ow[0], ow[1], ow[2], ow[3]);
        *(int4*)(dst + (((sp * 2 + 1 + rot) & 3) * 16)) = make_int4(ow[4], ow[5], ow[6], ow[7]);
    } else if (sl < NSEG + N_NODES) {
        int node = sl - NSEG;
        int rt = node >> 6, m = node & 63;
        const unsigned char* hp = &h8[(size_t)node * 256 + q * 32];
        int4 lo = *(const int4*)(hp + 0);
        int4 hi = *(const int4*)(hp + 16);
        int ks = 48 + q;
        int p = ks >> 1, sp = ks & 1;
        unsigned char* dst = Apk + ((size_t)(rt * 28 + p)) * 4096 + (size_t)m * 64;
        int rot = (m >> 1) & 3;
        *(int4*)(dst + (((sp * 2 + 0 + rot) & 3) * 16)) = lo;
        *(int4*)(dst + (((sp * 2 + 1 + rot) & 3) * 16)) = hi;
    }
}

// ================= layer-0 MFMA GEMM (bf16 in, fp8 h out) =================
__global__ __launch_bounds__(256)
void gemm_l0(const unsigned short* __restrict__ A, const unsigned short* __restrict__ Wt,
             const float* __restrict__ bias, unsigned char* __restrict__ outH8,
             int Ktot, int KB, int dout) {
    __shared__ unsigned short As[64 * 32];
    __shared__ unsigned short Bs[256 * 32];
    const int tid = threadIdx.x;
    const int col0 = blockIdx.x * 256;
    const int row0 = blockIdx.y * 64;
    const int w = tid >> 6, l = tid & 63;
    f32x4 acc[4][4] = {};

    for (int k0 = 0; k0 < Ktot; k0 += 32) {
        {
            int m = tid >> 2, slot = tid & 3;
            int4 v = {0, 0, 0, 0};
            int mg = row0 + m;
            if (mg < N_NODES) v = *(const int4*)&A[(size_t)mg * Ktot + k0 + slot * 8];
            *(int4*)&As[SWZ(m, slot)] = v;
        }
        {
            int nb = tid >> 2, slot = tid & 3;
            #pragma unroll
            for (int j = 0; j < 4; ++j) {
                int n = nb + j * 64;
                int4 v = *(const int4*)&Wt[(size_t)(col0 + n) * KB + k0 + slot * 8];
                *(int4*)&Bs[SWZ(n, slot)] = v;
            }
        }
        __syncthreads();
        bf16x8 af[4], bfr[4];
        #pragma unroll
        for (int rf = 0; rf < 4; ++rf)
            af[rf] = *(const bf16x8*)&As[SWZ(rf * 16 + (l & 15), l >> 4)];
        #pragma unroll
        for (int cf = 0; cf < 4; ++cf)
            bfr[cf] = *(const bf16x8*)&Bs[SWZ(w * 64 + cf * 16 + (l & 15), l >> 4)];
        #pragma unroll
        for (int cf = 0; cf < 4; ++cf)
            #pragma unroll
            for (int rf = 0; rf < 4; ++rf)
                acc[rf][cf] = __builtin_amdgcn_mfma_f32_16x16x32_bf16(
                    af[rf], bfr[cf], acc[rf][cf], 0, 0, 0);
        __syncthreads();
    }

    const int colbase = col0 + w * 64;
    #pragma unroll
    for (int cf = 0; cf < 4; ++cf) {
        int c = colbase + cf * 16 + (l & 15);
        float bb = bias[c];
        #pragma unroll
        for (int rf = 0; rf < 4; ++rf)
            #pragma unroll
            for (int i = 0; i < 4; ++i) {
                int m = row0 + rf * 16 + (l >> 4) * 4 + i;
                if (m < N_NODES) {
                    float v = fmaxf(acc[rf][cf][i] + bb, 0.f);
                    outH8[(size_t)m * dout + c] = fp8_1(v);
                }
            }
    }
}

// ====== layers 1-2: MX-scaled 32x32x64 fp8 GEMM, 4 waves, 64x64 per wave ======
// R22: counted-vmcnt deep pipeline (T3+T4), de-risked vs R21:
//   - 2 B-sets (set = pair&1), 32 VGPR; live regs ~112 < R17's ~128.
//   - single-load asm statements for B (simplest constraints).
//   - STAGE at superstep bottom: decouples A-staging from B-waits.
// Superstep S (reads buf S%3, pairs 4S..4S+3):
//   wait vmcnt(20)  [proves STAGE(S), issued bottom of S-2; 16 LOADB + 4 STAGE after]
//   s_barrier
//   phase q=0..3: READA(q); wait vmcnt(8,8,4,4); MFMA x4 (setprio); LOADB(4S+2+q)
//   STAGE(S+2 -> buf (S+2)%3)
// Prologue: STAGE(0); LOADB(0); LOADB(1); STAGE(1)  => S=0 top wait = 12,
// phase waits identical to steady state. Tail pairs/groups clamp (L2-hot).
__global__ __launch_bounds__(256, 3)
void gemm_mx(const unsigned char* __restrict__ Apk, const unsigned char* __restrict__ Wpk,
             const float* __restrict__ bias, unsigned char* __restrict__ outH8,
             unsigned* __restrict__ maxbuf, int dout, int fuse) {
    __shared__ __align__(16) unsigned char As[3][16384];
    __shared__ unsigned lmax[256];

    const int tid = threadIdx.x;
    const int w = tid >> 6, l = tid & 63;
    const int row0 = blockIdx.y * 64;
    const int bcol = blockIdx.x * 256;
    const int cg0 = bcol + w * 64;           // wave's global col origin
    const int ctIdx = cg0 >> 8;
    const int nOff = cg0 & 255;

    f32x16 acc[2][2] = {};
    i32x8 aF[2];
    i32x4 bq[2][4];                          // 2 B-sets x {cf0.lo, cf0.hi, cf1.lo, cf1.hi}

    const unsigned char* aBlock = Apk + (size_t)blockIdx.y * 28 * 4096;
    const unsigned char* bLane = Wpk + (size_t)ctIdx * 28 * 16384
                               + (size_t)(nOff + (l & 31)) * 64 + (size_t)(l >> 5) * 32;

#define SB() __builtin_amdgcn_sched_barrier(0)

#define STAGE(g, buf) do {                                                   \
        _Pragma("unroll")                                                    \
        for (int i = 0; i < 4; ++i) {                                        \
            int c = w * 4 + i;                                               \
            gl_lds16(aBlock + (size_t)(g) * 16384 + (size_t)c * 1024 + l * 16, \
                     &As[buf][c * 1024]);                                    \
        }                                                                    \
    } while (0)

#define LOADB(p, s) do {                                                     \
        const unsigned char* _bp = bLane + (size_t)(p) * 16384;              \
        asm volatile("global_load_dwordx4 %0, %1, off"                       \
                     : "=&v"(bq[s][0]) : "v"(_bp));                          \
        asm volatile("global_load_dwordx4 %0, %1, off offset:16"             \
                     : "=&v"(bq[s][1]) : "v"(_bp));                          \
        asm volatile("global_load_dwordx4 %0, %1, off offset:2048"           \
                     : "=&v"(bq[s][2]) : "v"(_bp));                          \
        asm volatile("global_load_dwordx4 %0, %1, off offset:2064"           \
                     : "=&v"(bq[s][3]) : "v"(_bp));                          \
    } while (0)

#define READA(buf, q) do {                                                   \
        _Pragma("unroll")                                                    \
        for (int rf = 0; rf < 2; ++rf) {                                     \
            int mrow = rf * 32 + (l & 31);                                   \
            int rot = (mrow >> 1) & 3;                                       \
            int g = (l >> 5) * 2;                                            \
            const unsigned char* base = &As[buf][(q) * 4096 + (size_t)mrow * 64]; \
            i32x4 lo = *(const i32x4*)(base + (((g + 0 + rot) & 3) * 16));   \
            i32x4 hi = *(const i32x4*)(base + (((g + 1 + rot) & 3) * 16));   \
            i32x8 r;                                                         \
            r[0] = lo[0]; r[1] = lo[1]; r[2] = lo[2]; r[3] = lo[3];          \
            r[4] = hi[0]; r[5] = hi[1]; r[6] = hi[2]; r[7] = hi[3];          \
            aF[rf] = r;                                                      \
        }                                                                    \
    } while (0)

#define DOMFMA(s) do {                                                       \
        i32x8 Bq0, Bq1;                                                      \
        Bq0[0] = bq[s][0][0]; Bq0[1] = bq[s][0][1];                          \
        Bq0[2] = bq[s][0][2]; Bq0[3] = bq[s][0][3];                          \
        Bq0[4] = bq[s][1][0]; Bq0[5] = bq[s][1][1];                          \
        Bq0[6] = bq[s][1][2]; Bq0[7] = bq[s][1][3];                          \
        Bq1[0] = bq[s][2][0]; Bq1[1] = bq[s][2][1];                          \
        Bq1[2] = bq[s][2][2]; Bq1[3] = bq[s][2][3];                          \
        Bq1[4] = bq[s][3][0]; Bq1[5] = bq[s][3][1];                          \
        Bq1[6] = bq[s][3][2]; Bq1[7] = bq[s][3][3];                          \
        acc[0][0] = __builtin_amdgcn_mfma_scale_f32_32x32x64_f8f6f4(         \
            aF[0], Bq0, acc[0][0], 0, 0, 0, 127, 0, 123);                    \
        acc[1][0] = __builtin_amdgcn_mfma_scale_f32_32x32x64_f8f6f4(         \
            aF[1], Bq0, acc[1][0], 0, 0, 0, 127, 0, 123);                    \
        acc[0][1] = __builtin_amdgcn_mfma_scale_f32_32x32x64_f8f6f4(         \
            aF[0], Bq1, acc[0][1], 0, 0, 0, 127, 0, 123);                    \
        acc[1][1] = __builtin_amdgcn_mfma_scale_f32_32x32x64_f8f6f4(         \
            aF[1], Bq1, acc[1][1], 0, 0, 0, 127, 0, 123);                    \
    } while (0)

#define PHASE(buf, q, s, WN, p) do {                                         \
        READA(buf, q);                                                       \
        asm volatile("s_waitcnt vmcnt(" WN ")");                             \
        SB();                                                                \
        __builtin_amdgcn_s_setprio(1);                                       \
        DOMFMA(s);                                                           \
        __builtin_amdgcn_s_setprio(0);                                       \
        SB();                                                                \
        LOADB(p, s);                                                         \
        SB();                                                                \
    } while (0)

#define SSTEP(S, TW) do {                                                    \
        asm volatile("s_waitcnt vmcnt(" TW ")");                             \
        SB();                                                                \
        __builtin_amdgcn_s_barrier();                                        \
        SB();                                                                \
        PHASE((S) % 3, 0, 0, "8", 4 * (S) + 2 <= 27 ? 4 * (S) + 2 : 27);     \
        PHASE((S) % 3, 1, 1, "8", 4 * (S) + 3 <= 27 ? 4 * (S) + 3 : 27);     \
        PHASE((S) % 3, 2, 0, "4", 4 * (S) + 4 <= 27 ? 4 * (S) + 4 : 27);     \
        PHASE((S) % 3, 3, 1, "4", 4 * (S) + 5 <= 27 ? 4 * (S) + 5 : 27);     \
        STAGE((S) + 2 <= 6 ? (S) + 2 : 6, ((S) + 2) % 3);                    \
        SB();                                                                \
    } while (0)

    // ---- prologue: STAGE(0); B pairs 0,1; STAGE(1) ----
    STAGE(0, 0);
    SB();
    LOADB(0, 0);
    LOADB(1, 1);
    SB();
    STAGE(1, 1);
    SB();

    // ---- 7 supersteps, fully unrolled ----
    SSTEP(0, "12");
    SSTEP(1, "20");
    SSTEP(2, "20");
    SSTEP(3, "20");
    SSTEP(4, "20");
    SSTEP(5, "20");
    SSTEP(6, "20");

#undef SSTEP
#undef PHASE
#undef DOMFMA
#undef READA
#undef LOADB
#undef STAGE
#undef SB

    if (!fuse) {
        #pragma unroll
        for (int cf = 0; cf < 2; ++cf) {
            int c = cg0 + cf * 32 + (l & 31);
            float bb = bias[c];
            #pragma unroll
            for (int rf = 0; rf < 2; ++rf)
                #pragma unroll
                for (int reg = 0; reg < 16; ++reg) {
                    int m = row0 + rf * 32 + (reg & 3) + 8 * (reg >> 2) + 4 * (l >> 5);
                    if (m < N_NODES) {
                        float v = fmaxf(acc[rf][cf][reg] + bb, 0.f);
                        outH8[(size_t)m * dout + c] = fp8_1(v);
                    }
                }
        }
    } else {
        lmax[tid] = 0u;
        __syncthreads();
        #pragma unroll
        for (int cf = 0; cf < 2; ++cf) {
            int c = cg0 + cf * 32 + (l & 31);
            float bb = bias[c];
            float mv = 0.f;
            bool any = false;
            #pragma unroll
            for (int rf = 0; rf < 2; ++rf)
                #pragma unroll
                for (int reg = 0; reg < 16; ++reg) {
                    int m = row0 + rf * 32 + (reg & 3) + 8 * (reg >> 2) + 4 * (l >> 5);
                    if (m < N_NODES) {
                        float v = acc[rf][cf][reg] + bb;
                        mv = any ? fmaxf(mv, v) : v;
                        any = true;
                    }
                }
            if (any) atomicMax(&lmax[c - bcol], enc_f32(mv));
        }
        __syncthreads();
        atomicMax(&maxbuf[bcol + tid], lmax[tid]);
    }
}

// ================= finalize =================
__global__ void finalize_kernel(const unsigned* __restrict__ maxbuf,
                                float* __restrict__ out) {
    __shared__ float red[8];
    int c = threadIdx.x;
    float v = dec_f32(maxbuf[c]);
    v = fmaxf(v, 0.0f);
    float t = tanhf(v);
    float s = t * t;
    #pragma unroll
    for (int o = 32; o > 0; o >>= 1) s += __shfl_down(s, o);
    int wid = c >> 6;
    if ((c & 63) == 0) red[wid] = s;
    __syncthreads();
    if (c < 8) {
        float wsum = red[c];
        #pragma unroll
        for (int o = 4; o > 0; o >>= 1) wsum += __shfl_down(wsum, o);
        if (c == 0) red[0] = wsum;
    }
    __syncthreads();
    float norm = sqrtf(red[0]);
    out[c] = t / norm;
}

static inline size_t align_up(size_t v, size_t a) { return (v + a - 1) / a * a; }

extern "C" void kernel_launch(void* const* d_in, const int* in_sizes, int n_in,
                              void* d_out, int out_size, void* d_ws, size_t ws_size,
                              hipStream_t stream) {
    const float* x  = (const float*)d_in[0];
    const int*   ei = (const int*)d_in[1];
    const int*   et = (const int*)d_in[2];
    const float* W0 = (const float*)d_in[3];
    const float* r0 = (const float*)d_in[4];
    const float* b0 = (const float*)d_in[5];
    const float* W1 = (const float*)d_in[6];
    const float* r1 = (const float*)d_in[7];
    const float* b1 = (const float*)d_in[8];
    const float* W2 = (const float*)d_in[9];
    const float* r2 = (const float*)d_in[10];
    const float* b2 = (const float*)d_in[11];
    float* out = (float*)d_out;

    // ---- workspace layout (~140 MB) ----
    char* ws = (char*)d_ws;
    size_t off = 0;
    int* cntpart = (int*)(ws + off); off = align_up(off + (size_t)NSEG * 4, 256);
    int* bsum = (int*)(ws + off);    off = align_up(off + 512 * 4, 256);
    int* rowptr = (int*)(ws + off);  off = align_up(off + (size_t)(NSEG + 1) * 4, 256);
    int* fillptr = (int*)(ws + off); off = align_up(off + (size_t)NSEG * 4, 256);
    int* esrc = (int*)(ws + off);    off = align_up(off + (size_t)N_EDGES * 4, 256);
    float* rcp = (float*)(ws + off); off = align_up(off + (size_t)NSEG * 4, 256);
    unsigned* maxbuf = (unsigned*)(ws + off); off = align_up(off + 512 * 4, 256);
    unsigned short* Wt0 = (unsigned short*)(ws + off); off = align_up(off + (size_t)256 * 160 * 2, 256);
    unsigned char* Wpk1 = (unsigned char*)(ws + off); off = align_up(off + (size_t)1 * 28 * 16384, 256);
    unsigned char* Wpk2 = (unsigned char*)(ws + off); off = align_up(off + (size_t)2 * 28 * 16384, 256);
    unsigned char* hbuf1 = (unsigned char*)(ws + off); off = align_up(off + (size_t)N_NODES * 256, 256);
    unsigned char* hbuf2 = (unsigned char*)(ws + off); off = align_up(off + (size_t)N_NODES * 256, 256);
    unsigned short* Abf0 = (unsigned short*)(ws + off); off = align_up(off + (size_t)N_NODES * 160 * 2, 256);
    unsigned char* Apk = (unsigned char*)(ws + off); off = align_up(off + (size_t)NTILE * 28 * 4096, 256);
    if (ws_size < off) return;  // workspace too small — clean bail

    // ---- CSR build ----
    hipMemsetAsync(cntpart, 0, (size_t)NSEG * 4, stream);
    count_seg<<<(N_EDGES + 255) / 256, 256, 0, stream>>>(ei, et, cntpart);
    scan1<<<SCAN_NB, 256, 0, stream>>>(cntpart, bsum);
    scan2<<<1, 512, 0, stream>>>(bsum);
    scan3<<<SCAN_NB, 256, 0, stream>>>(cntpart, bsum, rowptr, fillptr);
    rcp_kernel<<<(NSEG + 255) / 256, 256, 0, stream>>>(rowptr, rcp);
    fill_edges<<<(N_EDGES + 255) / 256, 256, 0, stream>>>(ei, et, fillptr, esrc);
    hipMemsetAsync(maxbuf, 0, 512 * 4, stream);

    // ---- weight prep ----
    prep_w0<<<dim3(160, 1), 256, 0, stream>>>(W0, r0, Wt0, 120, 20, 256, 160);
    prep_wpk8<<<dim3(1792, 1), 256, 0, stream>>>(W1, r1, Wpk1, 1536, 256);
    prep_wpk8<<<dim3(1792, 2), 256, 0, stream>>>(W2, r2, Wpk2, 1536, 512);

    // ---- layer 0 (bf16 GEMM, fp8 h1 out) ----
    hipMemsetAsync(Abf0, 0, (size_t)N_NODES * 160 * 2, stream);
    gather0<<<(NSEG * 5 + 255) / 256, 256, 0, stream>>>(x, rowptr, esrc, rcp, Abf0);
    copyx0<<<(N_NODES * 32 + 255) / 256, 256, 0, stream>>>(x, Abf0);
    gemm_l0<<<dim3(1, NTILE), 256, 0, stream>>>(Abf0, Wt0, b0, hbuf1, 160, 160, 256);

    const int gthreads = (NSEG + N_NODES) * 8;

    // ---- layer 1: MX pair-packed fp8 A-panel -> gemm_mx (64x256), dout=256 ----
    gather_all8<<<(gthreads + 255) / 256, 256, 0, stream>>>(hbuf1, rowptr, esrc, rcp, Apk);
    gemm_mx<<<dim3(1, NTILE), 256, 0, stream>>>(Apk, Wpk1, b1, hbuf2, nullptr, 256, 0);

    // ---- layer 2: MX pair-packed fp8 A-panel -> gemm_mx (64x256 x2) + max-pool, dout=512 ----
    gather_all8<<<(gthreads + 255) / 256, 256, 0, stream>>>(hbuf2, rowptr, esrc, rcp, Apk);
    gemm_mx<<<dim3(2, NTILE), 256, 0, stream>>>(Apk, Wpk2, b2, nullptr, maxbuf, 512, 1);

    finalize_kernel<<<1, 512, 0, stream>>>(maxbuf, out);
}